// Round 1
// baseline (33961.938 us; speedup 1.0000x reference)
//
#include <hip/hip_runtime.h>
#include <math.h>

#define SEQ    512
#define BATCH  64
#define IN_    64
#define HID    512
#define MID    256
#define CONCAT (IN_ + 2 * HID)   // 1088
#define ZS     (IN_ + MID)       // 320

// One workgroup per batch element. Carry (m, s) lives in LDS; weights are
// streamed from L2 each step (all 64 WGs read identical addresses -> L2 hits).
// Phase A: z_mid[j] = tanh(W_z[j] . [x_t, m, 1/s] + b_z[j]), 4 threads/row.
// Phase B: new_s/new_m via W_s/W_m . [x_t, z_mid], 2 threads/row, fused loop.
__global__ __launch_bounds__(1024, 1)
void metamu_scan_kernel(const float* __restrict__ x,      // [SEQ][BATCH][IN_]
                        const float* __restrict__ old_m,  // [BATCH][HID]
                        const float* __restrict__ old_s,  // [BATCH][HID]
                        const float* __restrict__ W_z,    // [MID][CONCAT]
                        const float* __restrict__ b_z,    // [MID]
                        const float* __restrict__ W_s,    // [HID][ZS]
                        const float* __restrict__ b_s,    // [HID]
                        const float* __restrict__ W_m,    // [HID][ZS]
                        const float* __restrict__ b_m,    // [HID]
                        float* __restrict__ out)          // out_m then out_s
{
    const int b   = blockIdx.x;
    const int tid = threadIdx.x;

    __shared__ __align__(16) float zin[CONCAT];   // [x_t | m | 1/s]
    __shared__ __align__(16) float zvec[ZS];      // [x_t | z_mid]
    __shared__ float m_state[HID];
    __shared__ float s_state[HID];

    // init carry
    for (int h = tid; h < HID; h += 1024) {
        m_state[h] = old_m[b * HID + h];
        s_state[h] = old_s[b * HID + h];
    }
    __syncthreads();

    float* __restrict__ out_m = out;
    float* __restrict__ out_s = out + (size_t)SEQ * BATCH * HID;

    // fixed per-thread roles
    const int j  = tid >> 2, l4 = tid & 3;   // phase A: row j of W_z, 4 lanes/row
    const int h  = tid >> 1, l2 = tid & 1;   // phase B: row h of W_s/W_m, 2 lanes/row
    const float4* __restrict__ wzr = reinterpret_cast<const float4*>(W_z + (size_t)j * CONCAT);
    const float4* __restrict__ wsr = reinterpret_cast<const float4*>(W_s + (size_t)h * ZS);
    const float4* __restrict__ wmr = reinterpret_cast<const float4*>(W_m + (size_t)h * ZS);
    const float bz = b_z[j];
    const float bs = b_s[h];
    const float bm = b_m[h];

    for (int t = 0; t < SEQ; ++t) {
        // ---- stage z_inpt = [x_t, m, 1/s] and x_t part of zvec ----
        if (tid < IN_) {
            float v = x[((size_t)t * BATCH + b) * IN_ + tid];
            zin[tid]  = v;
            zvec[tid] = v;
        }
        for (int hh = tid; hh < HID; hh += 1024) {
            zin[IN_ + hh]       = m_state[hh];
            zin[IN_ + HID + hh] = 1.0f / s_state[hh];
        }
        __syncthreads();

        // ---- phase A: z_mid (256 rows, K=1088), 4 threads per row ----
        {
            float a0 = 0.f, a1 = 0.f;
            #pragma unroll
            for (int i = 0; i < 34; ++i) {
                const int sl0 = l4 + 8 * i;
                const int sl1 = sl0 + 4;
                float4 w0 = wzr[sl0];
                float4 w1 = wzr[sl1];
                float4 z0 = *reinterpret_cast<const float4*>(&zin[sl0 * 4]);
                float4 z1 = *reinterpret_cast<const float4*>(&zin[sl1 * 4]);
                a0 += w0.x * z0.x + w0.y * z0.y + w0.z * z0.z + w0.w * z0.w;
                a1 += w1.x * z1.x + w1.y * z1.y + w1.z * z1.z + w1.w * z1.w;
            }
            float az = a0 + a1;
            az += __shfl_xor(az, 1);
            az += __shfl_xor(az, 2);
            if (l4 == 0) zvec[IN_ + j] = tanhf(az + bz);
        }
        __syncthreads();

        // ---- phase B: new_s / new_m (512 rows each, K=320), 2 threads/row ----
        {
            float s0 = 0.f, s1 = 0.f, m0 = 0.f, m1 = 0.f;
            #pragma unroll
            for (int k = 0; k < 20; ++k) {
                const int sl0 = l2 + 4 * k;
                const int sl1 = sl0 + 2;
                float4 z0 = *reinterpret_cast<const float4*>(&zvec[sl0 * 4]);
                float4 z1 = *reinterpret_cast<const float4*>(&zvec[sl1 * 4]);
                float4 w0 = wsr[sl0];
                float4 w1 = wsr[sl1];
                s0 += w0.x * z0.x + w0.y * z0.y + w0.z * z0.z + w0.w * z0.w;
                s1 += w1.x * z1.x + w1.y * z1.y + w1.z * z1.z + w1.w * z1.w;
                float4 v0 = wmr[sl0];
                float4 v1 = wmr[sl1];
                m0 += v0.x * z0.x + v0.y * z0.y + v0.z * z0.z + v0.w * z0.w;
                m1 += v1.x * z1.x + v1.y * z1.y + v1.z * z1.z + v1.w * z1.w;
            }
            float ss = s0 + s1;
            float mv = m0 + m1;
            ss += __shfl_xor(ss, 1);
            mv += __shfl_xor(mv, 1);
            if (l2 == 0) {
                float sold = s_state[h];
                float ns   = sold + 1.0f / (1.0f + expf(-(ss + bs)));
                float gate = sold / ns;                       // uses old s, new s
                float nm   = gate * m_state[h] + (1.0f - gate) * tanhf(mv + bm);
                s_state[h] = ns;
                m_state[h] = nm;
                const size_t o = ((size_t)t * BATCH + b) * HID + h;
                out_m[o] = nm;
                out_s[o] = ns;
            }
        }
        __syncthreads();   // protect m_state/s_state before next staging
    }
}

extern "C" void kernel_launch(void* const* d_in, const int* in_sizes, int n_in,
                              void* d_out, int out_size, void* d_ws, size_t ws_size,
                              hipStream_t stream) {
    const float* x     = (const float*)d_in[0];
    const float* old_m = (const float*)d_in[1];
    const float* old_s = (const float*)d_in[2];
    const float* W_z   = (const float*)d_in[3];
    const float* b_z   = (const float*)d_in[4];
    const float* W_s   = (const float*)d_in[5];
    const float* b_s   = (const float*)d_in[6];
    const float* W_m   = (const float*)d_in[7];
    const float* b_m   = (const float*)d_in[8];

    metamu_scan_kernel<<<dim3(BATCH), dim3(1024), 0, stream>>>(
        x, old_m, old_s, W_z, b_z, W_s, b_s, W_m, b_m, (float*)d_out);
}

// Round 2
// 30305.124 us; speedup vs baseline: 1.1207x; 1.1207x over previous
//
#include <hip/hip_runtime.h>
#include <math.h>
#include <stdint.h>

#define SEQ    512
#define BATCH  64
#define IN_    64
#define HID    512
#define MID    256
#define CONCAT 1088
#define ZS     320

typedef _Float16 h2t __attribute__((ext_vector_type(2)));

__device__ __forceinline__ float fdot2(h2t a, h2t b, float c) {
    return __builtin_amdgcn_fdot2(a, b, c, false);
}
__device__ __forceinline__ uint32_t pack2(float a, float b) {
    return __builtin_bit_cast(uint32_t, __builtin_amdgcn_cvt_pkrtz(a, b));
}

// One WG (1024 threads) per batch element; weights resident in VGPRs as fp16.
// Phase A: z_mid = tanh(W_z @ [x,m,1/s] + b_z). Thread (g=tid>>4, c=tid&15)
//   owns rows 4g..4g+3, K-chunk c of 68 elems. Reduce over 16 c-lanes.
// Phase B: new_s/new_m. Thread (gb=tid>>3, cb=tid&7) owns h=4gb..4gb+3 for
//   both W_s and W_m (8 virtual rows), K-chunk cb of 40 elems. Reduce over 8.
__global__ __launch_bounds__(1024, 1)
void metamu_scan_kernel(const float* __restrict__ x,      // [SEQ][BATCH][IN_]
                        const float* __restrict__ old_m,  // [BATCH][HID]
                        const float* __restrict__ old_s,  // [BATCH][HID]
                        const float* __restrict__ W_z,    // [MID][CONCAT]
                        const float* __restrict__ b_z,
                        const float* __restrict__ W_s,    // [HID][ZS]
                        const float* __restrict__ b_s,
                        const float* __restrict__ W_m,    // [HID][ZS]
                        const float* __restrict__ b_m,
                        float* __restrict__ out)
{
    const int b   = blockIdx.x;
    const int tid = threadIdx.x;

    // zin chunks padded: 16 chunks x 36 half2-words (34 used), 144B stride.
    __shared__ __align__(16) uint32_t zinA[16 * 36];
    __shared__ __align__(16) uint32_t zvecB[8 * 20];   // 8 chunks x 20 words (80B)
    __shared__ __align__(16) float m_state[HID];
    __shared__ __align__(16) float s_state[HID];

    // ---- init carry ----
    for (int h = tid; h < HID; h += 1024) {
        m_state[h] = old_m[b * HID + h];
        s_state[h] = old_s[b * HID + h];
    }

    const int g  = tid >> 4, c  = tid & 15;
    const int gb = tid >> 3, cb = tid & 7;

    // ---- weights -> registers (fp16 packed, RTN one-time converts) ----
    h2t wA[4][34];
    #pragma unroll
    for (int r = 0; r < 4; ++r) {
        const float* Wrow = W_z + (size_t)(4 * g + r) * CONCAT + c * 68;
        #pragma unroll
        for (int i = 0; i < 34; ++i) {
            float2 wf = *reinterpret_cast<const float2*>(Wrow + 2 * i);
            wA[r][i] = h2t{(_Float16)wf.x, (_Float16)wf.y};
        }
    }
    h2t wB[8][20];
    #pragma unroll
    for (int r = 0; r < 8; ++r) {
        const float* Wp   = (r & 1) ? W_m : W_s;
        const float* Wrow = Wp + (size_t)(4 * gb + (r >> 1)) * ZS + cb * 40;
        #pragma unroll
        for (int i = 0; i < 20; ++i) {
            float2 wf = *reinterpret_cast<const float2*>(Wrow + 2 * i);
            wB[r][i] = h2t{(_Float16)wf.x, (_Float16)wf.y};
        }
    }

    float bz[4] = {0, 0, 0, 0};
    if (c == 0) {
        #pragma unroll
        for (int r = 0; r < 4; ++r) bz[r] = b_z[4 * g + r];
    }
    float bs[4] = {0, 0, 0, 0}, bm[4] = {0, 0, 0, 0};
    if (cb == 0) {
        #pragma unroll
        for (int q = 0; q < 4; ++q) { bs[q] = b_s[4 * gb + q]; bm[q] = b_m[4 * gb + q]; }
    }

    float* __restrict__ out_m = out;
    float* __restrict__ out_s = out + (size_t)SEQ * BATCH * HID;

    // prefetch x for t=0 (threads 0..31 hold pair e=2*tid)
    float2 xv = {0.f, 0.f};
    if (tid < 32) xv = *reinterpret_cast<const float2*>(x + (size_t)b * IN_ + 2 * tid);

    __syncthreads();

    for (int t = 0; t < SEQ; ++t) {
        // ---- staging: zin = [x | m | 1/s] packed half2 into chunked layout ----
        if (tid < 544) {
            const int e = 2 * tid;
            float v0, v1;
            if (e < 64) { v0 = xv.x; v1 = xv.y; }
            else if (e < 576) {
                float2 mv = *reinterpret_cast<const float2*>(&m_state[e - 64]);
                v0 = mv.x; v1 = mv.y;
            } else {
                float2 sv = *reinterpret_cast<const float2*>(&s_state[e - 576]);
                v0 = __builtin_amdgcn_rcpf(sv.x);
                v1 = __builtin_amdgcn_rcpf(sv.y);
            }
            uint32_t p = pack2(v0, v1);
            zinA[(e / 68) * 36 + ((e % 68) >> 1)] = p;
            if (e < 64) zvecB[(e / 40) * 20 + ((e % 40) >> 1)] = p;  // x part of z
        }
        __syncthreads();

        // prefetch next x (hides under phase A compute)
        if (tid < 32 && t + 1 < SEQ)
            xv = *reinterpret_cast<const float2*>(x + ((size_t)(t + 1) * BATCH + b) * IN_ + 2 * tid);

        // ---- phase A: z_mid rows 4g..4g+3 ----
        {
            uint32_t zf[34];
            #pragma unroll
            for (int i = 0; i < 8; ++i) {
                uint4 v = *reinterpret_cast<const uint4*>(&zinA[c * 36 + 4 * i]);
                zf[4 * i] = v.x; zf[4 * i + 1] = v.y; zf[4 * i + 2] = v.z; zf[4 * i + 3] = v.w;
            }
            {
                uint2 v = *reinterpret_cast<const uint2*>(&zinA[c * 36 + 32]);
                zf[32] = v.x; zf[33] = v.y;
            }
            float acc[4] = {0.f, 0.f, 0.f, 0.f};
            #pragma unroll
            for (int i = 0; i < 34; ++i) {
                h2t z = __builtin_bit_cast(h2t, zf[i]);
                #pragma unroll
                for (int r = 0; r < 4; ++r) acc[r] = fdot2(wA[r][i], z, acc[r]);
            }
            #pragma unroll
            for (int r = 0; r < 4; ++r) {
                acc[r] += __shfl_xor(acc[r], 1);
                acc[r] += __shfl_xor(acc[r], 2);
                acc[r] += __shfl_xor(acc[r], 4);
                acc[r] += __shfl_xor(acc[r], 8);
            }
            if (c == 0) {
                float z0 = tanhf(acc[0] + bz[0]);
                float z1 = tanhf(acc[1] + bz[1]);
                float z2 = tanhf(acc[2] + bz[2]);
                float z3 = tanhf(acc[3] + bz[3]);
                const int e0 = 64 + 4 * g;                 // z element index
                const int w0 = (e0 / 40) * 20 + ((e0 % 40) >> 1);
                zvecB[w0]     = pack2(z0, z1);
                zvecB[w0 + 1] = pack2(z2, z3);
            }
        }
        __syncthreads();

        // ---- phase B: new_s/new_m for h = 4gb..4gb+3 ----
        {
            uint32_t zf[20];
            #pragma unroll
            for (int i = 0; i < 5; ++i) {
                uint4 v = *reinterpret_cast<const uint4*>(&zvecB[cb * 20 + 4 * i]);
                zf[4 * i] = v.x; zf[4 * i + 1] = v.y; zf[4 * i + 2] = v.z; zf[4 * i + 3] = v.w;
            }
            float acc[8] = {0.f, 0.f, 0.f, 0.f, 0.f, 0.f, 0.f, 0.f};
            #pragma unroll
            for (int i = 0; i < 20; ++i) {
                h2t z = __builtin_bit_cast(h2t, zf[i]);
                #pragma unroll
                for (int r = 0; r < 8; ++r) acc[r] = fdot2(wB[r][i], z, acc[r]);
            }
            #pragma unroll
            for (int r = 0; r < 8; ++r) {
                acc[r] += __shfl_xor(acc[r], 1);
                acc[r] += __shfl_xor(acc[r], 2);
                acc[r] += __shfl_xor(acc[r], 4);
            }
            if (cb == 0) {
                float nsv[4], nmv[4];
                #pragma unroll
                for (int q = 0; q < 4; ++q) {
                    const int h = 4 * gb + q;
                    float sold = s_state[h];
                    float mold = m_state[h];
                    float sig  = 1.0f / (1.0f + expf(-(acc[2 * q] + bs[q])));
                    float ns   = sold + sig;
                    float gate = sold / ns;                 // stop-grad gate: old_s/new_s
                    float nm   = gate * mold + (1.0f - gate) * tanhf(acc[2 * q + 1] + bm[q]);
                    nsv[q] = ns; nmv[q] = nm;
                }
                *reinterpret_cast<float4*>(&s_state[4 * gb]) = float4{nsv[0], nsv[1], nsv[2], nsv[3]};
                *reinterpret_cast<float4*>(&m_state[4 * gb]) = float4{nmv[0], nmv[1], nmv[2], nmv[3]};
                const size_t o = ((size_t)t * BATCH + b) * HID + 4 * gb;
                *reinterpret_cast<float4*>(&out_m[o]) = float4{nmv[0], nmv[1], nmv[2], nmv[3]};
                *reinterpret_cast<float4*>(&out_s[o]) = float4{nsv[0], nsv[1], nsv[2], nsv[3]};
            }
        }
        __syncthreads();   // state stable before next staging
    }
}

extern "C" void kernel_launch(void* const* d_in, const int* in_sizes, int n_in,
                              void* d_out, int out_size, void* d_ws, size_t ws_size,
                              hipStream_t stream) {
    const float* x     = (const float*)d_in[0];
    const float* old_m = (const float*)d_in[1];
    const float* old_s = (const float*)d_in[2];
    const float* W_z   = (const float*)d_in[3];
    const float* b_z   = (const float*)d_in[4];
    const float* W_s   = (const float*)d_in[5];
    const float* b_s   = (const float*)d_in[6];
    const float* W_m   = (const float*)d_in[7];
    const float* b_m   = (const float*)d_in[8];

    metamu_scan_kernel<<<dim3(BATCH), dim3(1024), 0, stream>>>(
        x, old_m, old_s, W_z, b_z, W_s, b_s, W_m, b_m, (float*)d_out);
}

// Round 3
// 6090.474 us; speedup vs baseline: 5.5762x; 4.9758x over previous
//
#include <hip/hip_runtime.h>
#include <math.h>
#include <stdint.h>

#define SEQ    512
#define BATCH  64
#define IN_    64
#define HID    512
#define MID    256
#define CONCAT 1088
#define ZS     320
#define NW     4      // workgroups per batch
#define QH     128    // HID/NW  (h rows per WG)
#define QZ     64     // MID/NW  (z_mid rows per WG)

typedef _Float16 h2t __attribute__((ext_vector_type(2)));

__device__ __forceinline__ float fdot2u(uint32_t a, uint32_t b, float c) {
    return __builtin_amdgcn_fdot2(__builtin_bit_cast(h2t, a),
                                  __builtin_bit_cast(h2t, b), c, false);
}
__device__ __forceinline__ uint32_t packrtz(float a, float b) {
    return __builtin_bit_cast(uint32_t, __builtin_amdgcn_cvt_pkrtz(a, b));
}
__device__ __forceinline__ uint32_t packrtn(float a, float b) {
    h2t h = { (_Float16)a, (_Float16)b };
    return __builtin_bit_cast(uint32_t, h);
}
template <int CTRL>
__device__ __forceinline__ float dpp_add(float v) {
    int o = __builtin_amdgcn_update_dpp(0, __builtin_bit_cast(int, v), CTRL, 0xF, 0xF, true);
    return v + __builtin_bit_cast(float, o);
}
// full sum over 16-lane DPP row (lanes l&15); result in every lane
__device__ __forceinline__ float red16(float v) {
    v = dpp_add<0xB1>(v);   // quad_perm xor1
    v = dpp_add<0x4E>(v);   // quad_perm xor2
    v = dpp_add<0x124>(v);  // row_ror:4
    v = dpp_add<0x128>(v);  // row_ror:8
    return v;
}
// full sum over 4-lane quad; result in every lane
__device__ __forceinline__ float red4(float v) {
    v = dpp_add<0xB1>(v);
    v = dpp_add<0x4E>(v);
    return v;
}
// zin is stored as 16 chunks of 34 u32 padded to 36 (16B-aligned chunk starts)
__device__ __forceinline__ int zidx(int k) { return (k / 34) * 36 + (k % 34); }

// 4 WGs per batch (w = quarter index). Each WG holds its weight quarter in
// VGPRs as packed fp16. Per-step cross-WG exchange of (z_mid, m, 1/s) via
// agent-scope global buffers + monotonic flag counters (LLC-coherent).
__global__ __launch_bounds__(512, 2)
void metamu4_kernel(const float* __restrict__ x,      // [SEQ][BATCH][IN_]
                    const float* __restrict__ old_m,  // [BATCH][HID]
                    const float* __restrict__ old_s,  // [BATCH][HID]
                    const float* __restrict__ W_z,    // [MID][CONCAT]
                    const float* __restrict__ b_z,
                    const float* __restrict__ W_s,    // [HID][ZS]
                    const float* __restrict__ b_s,
                    const float* __restrict__ W_m,    // [HID][ZS]
                    const float* __restrict__ b_m,
                    float* __restrict__ out,
                    unsigned* __restrict__ state_flag, // [BATCH][NW]
                    unsigned* __restrict__ zmid_flag,  // [BATCH][NW]
                    float* __restrict__ sx,            // [BATCH][2][NW][256]: m[128]|inv_s[128]
                    uint32_t* __restrict__ zx)         // [BATCH][2][NW][32] packed fp16 z_mid
{
    const int bid = blockIdx.x;
    const int b   = bid & 63;      // batch
    const int w   = bid >> 6;      // quarter 0..3  ({b, b+64, ...} -> same XCD heuristic)
    const int tid = threadIdx.x;

    __shared__ __align__(16) uint32_t zin[16 * 36];   // [x|m|1/s] fp16-packed, chunk-padded
    __shared__ __align__(16) uint32_t zvec[160];      // [x|z_mid] fp16-packed
    __shared__ float m_st[QH], s_st[QH], inv_st[QH];  // local fp32 state quarter

    const int g  = tid >> 4, c  = tid & 15;   // phase A: row-pair group, K-chunk lane
    const int gB = tid >> 2, cB = tid & 3;    // phase B: h row, K-chunk lane

    // ---- weights -> VGPRs (fp16 RTN), one-time ----
    uint32_t wA0[34], wA1[34];
    {
        const float* p0 = W_z + (size_t)(QZ * w + 2 * g) * CONCAT + 68 * c;
        const float* p1 = p0 + CONCAT;
        #pragma unroll
        for (int i = 0; i < 34; ++i) {
            float2 a  = *reinterpret_cast<const float2*>(p0 + 2 * i);
            float2 bb = *reinterpret_cast<const float2*>(p1 + 2 * i);
            wA0[i] = packrtn(a.x, a.y);
            wA1[i] = packrtn(bb.x, bb.y);
        }
    }
    uint32_t wS[40], wM[40];
    {
        const int h = QH * w + gB;
        const float* ps = W_s + (size_t)h * ZS + 80 * cB;
        const float* pm = W_m + (size_t)h * ZS + 80 * cB;
        #pragma unroll
        for (int i = 0; i < 40; ++i) {
            float2 a  = *reinterpret_cast<const float2*>(ps + 2 * i);
            float2 bb = *reinterpret_cast<const float2*>(pm + 2 * i);
            wS[i] = packrtn(a.x, a.y);
            wM[i] = packrtn(bb.x, bb.y);
        }
    }
    const float bz0 = b_z[QZ * w + 2 * g], bz1 = b_z[QZ * w + 2 * g + 1];
    const float bsv = b_s[QH * w + gB],   bmv = b_m[QH * w + gB];

    if (tid < QH) {
        m_st[tid] = old_m[b * HID + QH * w + tid];
        s_st[tid] = old_s[b * HID + QH * w + tid];
    }
    __syncthreads();

    float* __restrict__ out_m = out;
    float* __restrict__ out_s = out + (size_t)SEQ * BATCH * HID;

    for (int t = 0; t < SEQ; ++t) {
        const int par  = t & 1;         // buffers consumed/produced this step
        const int par2 = par ^ 1;       // state slot produced for step t+1

        // ---- wait for peers' state (t>=1), then stage zin = [x|m|1/s] ----
        if (t > 0 && tid < 3) {
            const int w2 = (w + 1 + tid) & 3;
            while (__hip_atomic_load(&state_flag[b * NW + w2], __ATOMIC_ACQUIRE,
                                     __HIP_MEMORY_SCOPE_AGENT) < (unsigned)t) {}
        }
        __syncthreads();

        if (t == 0) {
            if (tid < 256) {  // m section: zin u32 k = 32+tid
                float2 mv = *reinterpret_cast<const float2*>(old_m + b * HID + 2 * tid);
                zin[zidx(32 + tid)] = packrtz(mv.x, mv.y);
            } else {          // 1/s section: k = 288+j
                const int j = tid - 256;
                float2 sv = *reinterpret_cast<const float2*>(old_s + b * HID + 2 * j);
                zin[zidx(288 + j)] = packrtz(__builtin_amdgcn_rcpf(sv.x),
                                             __builtin_amdgcn_rcpf(sv.y));
            }
        } else {
            if (tid < 64) {              // local m quarter
                const uint32_t p = packrtz(m_st[2 * tid], m_st[2 * tid + 1]);
                zin[zidx(32 + 64 * w + tid)] = p;
            } else if (tid < 128) {      // local 1/s quarter
                const int j = tid - 64;
                zin[zidx(288 + 64 * w + j)] = packrtz(inv_st[2 * j], inv_st[2 * j + 1]);
            } else {                     // remote quarters (3 peers x 128 u32)
                const int r  = tid - 128;
                const int p  = r >> 7, idx = r & 127;
                const int w2 = (w + 1 + p) & 3;
                const float* slot = sx + (((size_t)b * 2 + par) * NW + w2) * 256;
                if (idx < 64) {
                    float v0 = __hip_atomic_load(&slot[2 * idx],     __ATOMIC_RELAXED, __HIP_MEMORY_SCOPE_AGENT);
                    float v1 = __hip_atomic_load(&slot[2 * idx + 1], __ATOMIC_RELAXED, __HIP_MEMORY_SCOPE_AGENT);
                    zin[zidx(32 + 64 * w2 + idx)] = packrtz(v0, v1);
                } else {
                    const int j = idx - 64;
                    float v0 = __hip_atomic_load(&slot[128 + 2 * j],     __ATOMIC_RELAXED, __HIP_MEMORY_SCOPE_AGENT);
                    float v1 = __hip_atomic_load(&slot[128 + 2 * j + 1], __ATOMIC_RELAXED, __HIP_MEMORY_SCOPE_AGENT);
                    zin[zidx(288 + 64 * w2 + j)] = packrtz(v0, v1);
                }
            }
        }
        if (tid < 32) {  // x pairs -> zin chunk 0 and zvec x-part
            float2 xv = *reinterpret_cast<const float2*>(
                x + ((size_t)t * BATCH + b) * IN_ + 2 * tid);
            const uint32_t p = packrtz(xv.x, xv.y);
            zin[zidx(tid)] = p;
            zvec[tid] = p;
        }
        __syncthreads();

        // ---- phase A: z_mid rows (2g, 2g+1) of this quarter, K split 16 ways ----
        {
            uint32_t zf[34];
            const uint32_t* zc = &zin[c * 36];
            #pragma unroll
            for (int i = 0; i < 8; ++i) {
                uint4 v = *reinterpret_cast<const uint4*>(zc + 4 * i);
                zf[4 * i] = v.x; zf[4 * i + 1] = v.y; zf[4 * i + 2] = v.z; zf[4 * i + 3] = v.w;
            }
            { uint2 v = *reinterpret_cast<const uint2*>(zc + 32); zf[32] = v.x; zf[33] = v.y; }
            float a0 = 0.f, a1 = 0.f;
            #pragma unroll
            for (int i = 0; i < 34; ++i) {
                a0 = fdot2u(wA0[i], zf[i], a0);
                a1 = fdot2u(wA1[i], zf[i], a1);
            }
            a0 = red16(a0);
            a1 = red16(a1);
            if (c == 0) {
                const uint32_t pz = packrtz(tanhf(a0 + bz0), tanhf(a1 + bz1));
                zvec[32 + 32 * w + g] = pz;
                __hip_atomic_store(&zx[(((size_t)b * 2 + par) * NW + w) * 32 + g], pz,
                                   __ATOMIC_RELAXED, __HIP_MEMORY_SCOPE_AGENT);
            }
        }
        __syncthreads();   // drain zx stores + local zvec writes

        if (tid == 0)
            __hip_atomic_store(&zmid_flag[b * NW + w], (unsigned)(t + 1),
                               __ATOMIC_RELEASE, __HIP_MEMORY_SCOPE_AGENT);
        if (tid < 3) {
            const int w2 = (w + 1 + tid) & 3;
            while (__hip_atomic_load(&zmid_flag[b * NW + w2], __ATOMIC_ACQUIRE,
                                     __HIP_MEMORY_SCOPE_AGENT) < (unsigned)(t + 1)) {}
        }
        __syncthreads();
        if (tid < 96) {    // stage peers' z_mid quarters
            const int p = tid >> 5, gg = tid & 31;
            const int w2 = (w + 1 + p) & 3;
            zvec[32 + 32 * w2 + gg] =
                __hip_atomic_load(&zx[(((size_t)b * 2 + par) * NW + w2) * 32 + gg],
                                  __ATOMIC_RELAXED, __HIP_MEMORY_SCOPE_AGENT);
        }
        __syncthreads();

        // ---- phase B: new_s/new_m for h = QH*w + gB, K split 4 ways ----
        {
            uint32_t zg[40];
            const uint32_t* zc2 = &zvec[40 * cB];
            #pragma unroll
            for (int i = 0; i < 10; ++i) {
                uint4 v = *reinterpret_cast<const uint4*>(zc2 + 4 * i);
                zg[4 * i] = v.x; zg[4 * i + 1] = v.y; zg[4 * i + 2] = v.z; zg[4 * i + 3] = v.w;
            }
            float as = 0.f, am = 0.f;
            #pragma unroll
            for (int i = 0; i < 40; ++i) {
                as = fdot2u(wS[i], zg[i], as);
                am = fdot2u(wM[i], zg[i], am);
            }
            as = red4(as);
            am = red4(am);
            if (cB == 0) {
                const float sold = s_st[gB], mold = m_st[gB];
                const float sig  = 1.f / (1.f + expf(-(as + bsv)));
                const float ns   = sold + sig;
                const float gate = sold / ns;     // stop-grad gate: old_s / new_s
                const float nm   = gate * mold + (1.f - gate) * tanhf(am + bmv);
                const float inv  = __builtin_amdgcn_rcpf(ns);
                s_st[gB] = ns; m_st[gB] = nm; inv_st[gB] = inv;
                const size_t o = ((size_t)t * BATCH + b) * HID + QH * w + gB;
                out_m[o] = nm;
                out_s[o] = ns;
                float* slot = sx + (((size_t)b * 2 + par2) * NW + w) * 256;
                __hip_atomic_store(&slot[gB],       nm,  __ATOMIC_RELAXED, __HIP_MEMORY_SCOPE_AGENT);
                __hip_atomic_store(&slot[128 + gB], inv, __ATOMIC_RELAXED, __HIP_MEMORY_SCOPE_AGENT);
            }
        }
        __syncthreads();   // drain state stores before flag
        if (tid == 0)
            __hip_atomic_store(&state_flag[b * NW + w], (unsigned)(t + 1),
                               __ATOMIC_RELEASE, __HIP_MEMORY_SCOPE_AGENT);
    }
}

extern "C" void kernel_launch(void* const* d_in, const int* in_sizes, int n_in,
                              void* d_out, int out_size, void* d_ws, size_t ws_size,
                              hipStream_t stream) {
    const float* x     = (const float*)d_in[0];
    const float* old_m = (const float*)d_in[1];
    const float* old_s = (const float*)d_in[2];
    const float* W_z   = (const float*)d_in[3];
    const float* b_z   = (const float*)d_in[4];
    const float* W_s   = (const float*)d_in[5];
    const float* b_s   = (const float*)d_in[6];
    const float* W_m   = (const float*)d_in[7];
    const float* b_m   = (const float*)d_in[8];

    // ws layout: [0,4096) flags (state at 0, zmid at 1024B) | sx 512KB | zx 64KB
    const size_t SX_BYTES = (size_t)BATCH * 2 * NW * 256 * 4;
    const size_t ZX_BYTES = (size_t)BATCH * 2 * NW * 32 * 4;
    if (ws_size < 4096 + SX_BYTES + ZX_BYTES) return;  // insufficient scratch: bail

    unsigned* state_flag = (unsigned*)d_ws;
    unsigned* zmid_flag  = (unsigned*)((char*)d_ws + 1024);
    float*    sx         = (float*)((char*)d_ws + 4096);
    uint32_t* zx         = (uint32_t*)((char*)d_ws + 4096 + SX_BYTES);

    hipMemsetAsync(d_ws, 0, 4096, stream);  // reset flag counters each launch

    metamu4_kernel<<<dim3(BATCH * NW), dim3(512), 0, stream>>>(
        x, old_m, old_s, W_z, b_z, W_s, b_s, W_m, b_m,
        (float*)d_out, state_flag, zmid_flag, sx, zx);
}

// Round 4
// 3155.298 us; speedup vs baseline: 10.7635x; 1.9302x over previous
//
#include <hip/hip_runtime.h>
#include <math.h>
#include <stdint.h>

#define SEQ    512
#define BATCH  64
#define IN_    64
#define HID    512
#define MID    256
#define CONCAT 1088
#define ZS     320
#define NW     4      // workgroups per batch
#define QZ     64     // MID/NW: z_mid rows per WG

typedef _Float16 h2t __attribute__((ext_vector_type(2)));

__device__ __forceinline__ float fdot2u(uint32_t a, uint32_t b, float c) {
    return __builtin_amdgcn_fdot2(__builtin_bit_cast(h2t, a),
                                  __builtin_bit_cast(h2t, b), c, false);
}
__device__ __forceinline__ uint32_t packrtn(float a, float b) {
    h2t h = { (_Float16)a, (_Float16)b };
    return __builtin_bit_cast(uint32_t, h);
}
template <int CTRL>
__device__ __forceinline__ float dpp_add(float v) {
    int o = __builtin_amdgcn_update_dpp(0, __builtin_bit_cast(int, v), CTRL, 0xF, 0xF, true);
    return v + __builtin_bit_cast(float, o);
}
template <int CTRL>
__device__ __forceinline__ float dpp_get(float v) {   // fetch lane-permuted value
    int o = __builtin_amdgcn_update_dpp(0, __builtin_bit_cast(int, v), CTRL, 0xF, 0xF, true);
    return __builtin_bit_cast(float, o);
}
__device__ __forceinline__ float red16(float v) {     // sum over 16-lane group
    v = dpp_add<0xB1>(v);   // quad_perm xor1
    v = dpp_add<0x4E>(v);   // quad_perm xor2
    v = dpp_add<0x124>(v);  // row_ror:4
    v = dpp_add<0x128>(v);  // row_ror:8
    return v;
}
// zin: 16 chunks x 34 u32, padded to 36 (16B-aligned chunk base)
__device__ __forceinline__ int zidx(int k) { return (k / 34) * 36 + (k % 34); }

// Cross-WG partial-sum exchange buffer: [BATCH][2(parity)][NW][HID] u32
// (packed fp16 pair: lo = s-partial, hi = m-partial). Guarded by flags; never
// read before written within a launch, so no reset needed.
__device__ uint32_t g_px[(size_t)BATCH * 2 * NW * HID];

// 4 WGs per batch. WG w holds: W_z rows [64w,64w+64) (full K=1088), and
// W_s/W_m COLUMN slices {x cols 16w..16w+15} U {z cols 64+64w..64+64w+63}
// for ALL 512 rows (1 row per thread -> no reduce). One LLC exchange per
// step (partials); state finishing is redundant in all 4 WGs -> m,1/s local.
__global__ __launch_bounds__(512, 1)
void metamu5_kernel(const float* __restrict__ x,      // [SEQ][BATCH][IN_]
                    const float* __restrict__ old_m,  // [BATCH][HID]
                    const float* __restrict__ old_s,  // [BATCH][HID]
                    const float* __restrict__ W_z,    // [MID][CONCAT]
                    const float* __restrict__ b_z,
                    const float* __restrict__ W_s,    // [HID][ZS]
                    const float* __restrict__ b_s,
                    const float* __restrict__ W_m,    // [HID][ZS]
                    const float* __restrict__ b_m,
                    float* __restrict__ out,
                    unsigned* __restrict__ flag)      // [BATCH][NW] step counters
{
    const int bid = blockIdx.x;
    const int b   = bid & 63;      // batch
    const int w   = bid >> 6;      // quarter; blocks {b, b+64, ...} -> same XCD
    const int tid = threadIdx.x;
    const int h   = tid;           // phase-B / finish row (global h)

    __shared__ __align__(16) uint32_t zin[16 * 36]; // [x|m|1/s] fp16 pairs, chunked
    __shared__ __align__(16) uint32_t zvec[40];     // [x-slice(8) | z-quarter(32)]

    const int g = tid >> 4, c = tid & 15;           // phase A: row pair, K-chunk

    // ---- one-time: weights -> VGPRs (fp16 RTN) ----
    uint32_t wA0[34], wA1[34];
    {
        const float* p0 = W_z + (size_t)(QZ * w + 2 * g) * CONCAT + 68 * c;
        const float* p1 = p0 + CONCAT;
        #pragma unroll
        for (int i = 0; i < 34; ++i) {
            float2 a  = *reinterpret_cast<const float2*>(p0 + 2 * i);
            float2 bb = *reinterpret_cast<const float2*>(p1 + 2 * i);
            wA0[i] = packrtn(a.x, a.y);
            wA1[i] = packrtn(bb.x, bb.y);
        }
    }
    uint32_t wS[40], wM[40];
    {
        const float* ps = W_s + (size_t)h * ZS;
        const float* pm = W_m + (size_t)h * ZS;
        #pragma unroll
        for (int i = 0; i < 8; ++i) {   // x-col slice: cols 16w+2i
            float2 a  = *reinterpret_cast<const float2*>(ps + 16 * w + 2 * i);
            float2 bb = *reinterpret_cast<const float2*>(pm + 16 * w + 2 * i);
            wS[i] = packrtn(a.x, a.y);
            wM[i] = packrtn(bb.x, bb.y);
        }
        #pragma unroll
        for (int i = 0; i < 32; ++i) {  // z-col slice: cols 64+64w+2i
            float2 a  = *reinterpret_cast<const float2*>(ps + 64 + 64 * w + 2 * i);
            float2 bb = *reinterpret_cast<const float2*>(pm + 64 + 64 * w + 2 * i);
            wS[8 + i] = packrtn(a.x, a.y);
            wM[8 + i] = packrtn(bb.x, bb.y);
        }
    }
    const float bz0 = b_z[QZ * w + 2 * g], bz1 = b_z[QZ * w + 2 * g + 1];
    const float bsv = b_s[h], bmv = b_m[h];

    // ---- registers: full per-h state (redundant across the 4 WGs) ----
    float sreg = old_s[b * HID + h];
    float mreg = old_m[b * HID + h];

    // x prefetch: threads 0..31 hold float pair (2*tid, 2*tid+1)
    float2 xv = {0.f, 0.f};
    if (tid < 32) xv = *reinterpret_cast<const float2*>(x + (size_t)b * IN_ + 2 * tid);

    // ---- initial staging of zin(t=0) and zvec x-slice ----
    if (tid < 256) {
        float2 mv = *reinterpret_cast<const float2*>(old_m + b * HID + 2 * tid);
        zin[zidx(32 + tid)] = packrtn(mv.x, mv.y);
    } else {
        const int j = tid - 256;
        float2 sv = *reinterpret_cast<const float2*>(old_s + b * HID + 2 * j);
        zin[zidx(288 + j)] = packrtn(__builtin_amdgcn_rcpf(sv.x),
                                     __builtin_amdgcn_rcpf(sv.y));
    }
    if (tid < 32) zin[zidx(tid)] = packrtn(xv.x, xv.y);
    if (tid >= 8 * w && tid < 8 * w + 8) zvec[tid - 8 * w] = packrtn(xv.x, xv.y);
    __syncthreads();

    float* __restrict__ out_m = out;
    float* __restrict__ out_s = out + (size_t)SEQ * BATCH * HID;

    for (int t = 0; t < SEQ; ++t) {
        const int par = t & 1;

        // ---- phase A: z_mid rows (64w+2g, +1), K split over 16 lanes ----
        {
            uint32_t zf[34];
            const uint32_t* zc = &zin[c * 36];
            #pragma unroll
            for (int i = 0; i < 8; ++i) {
                uint4 v = *reinterpret_cast<const uint4*>(zc + 4 * i);
                zf[4 * i] = v.x; zf[4 * i + 1] = v.y; zf[4 * i + 2] = v.z; zf[4 * i + 3] = v.w;
            }
            { uint2 v = *reinterpret_cast<const uint2*>(zc + 32); zf[32] = v.x; zf[33] = v.y; }
            float a0 = 0.f, a1 = 0.f;
            #pragma unroll
            for (int i = 0; i < 34; ++i) {
                a0 = fdot2u(wA0[i], zf[i], a0);
                a1 = fdot2u(wA1[i], zf[i], a1);
            }
            a0 = red16(a0);
            a1 = red16(a1);
            if (c == 0)
                zvec[8 + g] = packrtn(tanhf(a0 + bz0), tanhf(a1 + bz1));
        }
        __syncthreads();

        // ---- phase B: partial (s,m) for row h over this WG's 80-col slice ----
        {
            uint32_t zg[40];
            #pragma unroll
            for (int i = 0; i < 10; ++i) {
                uint4 v = *reinterpret_cast<const uint4*>(&zvec[4 * i]);
                zg[4 * i] = v.x; zg[4 * i + 1] = v.y; zg[4 * i + 2] = v.z; zg[4 * i + 3] = v.w;
            }
            float as = 0.f, am = 0.f;
            #pragma unroll
            for (int i = 0; i < 40; ++i) {
                as = fdot2u(wS[i], zg[i], as);
                am = fdot2u(wM[i], zg[i], am);
            }
            // publish packed partial for row h
            __hip_atomic_store(&g_px[(((size_t)b * 2 + par) * NW + w) * HID + h],
                               packrtn(as, am),
                               __ATOMIC_RELAXED, __HIP_MEMORY_SCOPE_AGENT);
            __syncthreads();   // drain px stores (vmcnt) before flag release

            if (tid == 0)
                __hip_atomic_store(&flag[b * NW + w], (unsigned)(t + 1),
                                   __ATOMIC_RELEASE, __HIP_MEMORY_SCOPE_AGENT);
            // prefetch next x while waiting
            if (tid < 32 && t + 1 < SEQ)
                xv = *reinterpret_cast<const float2*>(
                    x + ((size_t)(t + 1) * BATCH + b) * IN_ + 2 * tid);
            if (tid < 3) {
                const int w2 = (w + 1 + tid) & 3;
                while (__hip_atomic_load(&flag[b * NW + w2], __ATOMIC_ACQUIRE,
                                         __HIP_MEMORY_SCOPE_AGENT) < (unsigned)(t + 1)) {}
            }
            __syncthreads();   // all peers' partials visible

            // ---- finish: sum 4 partials, state update for row h (redundant) ----
            #pragma unroll
            for (int p = 0; p < 3; ++p) {
                const int w2 = (w + 1 + p) & 3;
                uint32_t pk = __hip_atomic_load(
                    &g_px[(((size_t)b * 2 + par) * NW + w2) * HID + h],
                    __ATOMIC_RELAXED, __HIP_MEMORY_SCOPE_AGENT);
                h2t hv = __builtin_bit_cast(h2t, pk);
                as += (float)hv.x;
                am += (float)hv.y;
            }
            const float sig  = 1.f / (1.f + expf(-(as + bsv)));
            const float ns   = sreg + sig;
            const float gate = sreg / ns;              // stop-grad: old_s / new_s
            const float nm   = gate * mreg + (1.f - gate) * tanhf(am + bmv);
            const float inv  = __builtin_amdgcn_rcpf(ns);
            sreg = ns; mreg = nm;

            // owner WG writes output for its h-quarter
            if ((h >> 7) == w) {
                const size_t o = ((size_t)t * BATCH + b) * HID + h;
                out_m[o] = nm;
                out_s[o] = ns;
            }

            // ---- stage zin(t+1) + zvec x-slice in-register (DPP pair swap) ----
            const float nm_n  = dpp_get<0xB1>(nm);     // neighbor lane^1 value
            const float inv_n = dpp_get<0xB1>(inv);
            if ((tid & 1) == 0) {
                zin[zidx(32 + (tid >> 1))]  = packrtn(nm, nm_n);
                zin[zidx(288 + (tid >> 1))] = packrtn(inv, inv_n);
            }
            if (t + 1 < SEQ) {
                if (tid < 32) zin[zidx(tid)] = packrtn(xv.x, xv.y);
                if (tid >= 8 * w && tid < 8 * w + 8)
                    zvec[tid - 8 * w] = packrtn(xv.x, xv.y);
            }
        }
        __syncthreads();   // staging stable before next phase A
    }
}

extern "C" void kernel_launch(void* const* d_in, const int* in_sizes, int n_in,
                              void* d_out, int out_size, void* d_ws, size_t ws_size,
                              hipStream_t stream) {
    const float* x     = (const float*)d_in[0];
    const float* old_m = (const float*)d_in[1];
    const float* old_s = (const float*)d_in[2];
    const float* W_z   = (const float*)d_in[3];
    const float* b_z   = (const float*)d_in[4];
    const float* W_s   = (const float*)d_in[5];
    const float* b_s   = (const float*)d_in[6];
    const float* W_m   = (const float*)d_in[7];
    const float* b_m   = (const float*)d_in[8];

    if (ws_size < 4096) return;                 // flags live in d_ws
    unsigned* flag = (unsigned*)d_ws;
    hipMemsetAsync(d_ws, 0, 4096, stream);      // reset step counters each launch

    metamu5_kernel<<<dim3(BATCH * NW), dim3(512), 0, stream>>>(
        x, old_m, old_s, W_z, b_z, W_s, b_s, W_m, b_m, (float*)d_out, flag);
}

// Round 5
// 1370.542 us; speedup vs baseline: 24.7799x; 2.3022x over previous
//
#include <hip/hip_runtime.h>
#include <math.h>
#include <stdint.h>

#define SEQ    512
#define BATCH  64
#define IN_    64
#define HID    512
#define MID    256
#define CONCAT 1088
#define ZS     320
#define NW     4      // workgroups per batch
#define QZ     64     // MID/NW: z_mid rows per WG

typedef _Float16 h2t __attribute__((ext_vector_type(2)));

__device__ __forceinline__ float fdot2u(uint32_t a, uint32_t b, float c) {
    return __builtin_amdgcn_fdot2(__builtin_bit_cast(h2t, a),
                                  __builtin_bit_cast(h2t, b), c, false);
}
__device__ __forceinline__ uint32_t packrtn(float a, float b) {
    h2t h = { (_Float16)a, (_Float16)b };
    return __builtin_bit_cast(uint32_t, h);
}
template <int CTRL>
__device__ __forceinline__ float dpp_add(float v) {
    int o = __builtin_amdgcn_update_dpp(0, __builtin_bit_cast(int, v), CTRL, 0xF, 0xF, true);
    return v + __builtin_bit_cast(float, o);
}
template <int CTRL>
__device__ __forceinline__ float dpp_get(float v) {   // fetch lane-permuted value
    int o = __builtin_amdgcn_update_dpp(0, __builtin_bit_cast(int, v), CTRL, 0xF, 0xF, true);
    return __builtin_bit_cast(float, o);
}
__device__ __forceinline__ float red16(float v) {     // sum over 16-lane group
    v = dpp_add<0xB1>(v);   // quad_perm xor1
    v = dpp_add<0x4E>(v);   // quad_perm xor2
    v = dpp_add<0x124>(v);  // row_ror:4
    v = dpp_add<0x128>(v);  // row_ror:8
    return v;
}
// zin: 16 chunks x 34 u32, padded to 36 (16B-aligned chunk base)
__device__ __forceinline__ int zidx(int k) { return (k / 34) * 36 + (k % 34); }

// Stamped exchange buffer: [BATCH][2(parity)][NW][HID] u64 words.
// hi32 = step stamp (t+1), lo32 = packed fp16 (s-partial, m-partial).
// Atomic 8B word => data is self-validating; relaxed atomics suffice.
// Never reset: stamp-equality polling is safe across launches/replays.
__device__ uint64_t g_px[(size_t)BATCH * 2 * NW * HID];

// 4 WGs per batch. WG w holds: W_z rows [64w,64w+64) (full K=1088), and
// W_s/W_m COLUMN slices {x cols 16w..16w+15} U {z cols 64+64w..64+64w+63}
// for ALL 512 rows (1 thread per h row -> no reduce). One stamped-word LLC
// exchange per step; state finishing is redundant in all 4 WGs.
__global__ __launch_bounds__(512, 1)
void metamu6_kernel(const float* __restrict__ x,      // [SEQ][BATCH][IN_]
                    const float* __restrict__ old_m,  // [BATCH][HID]
                    const float* __restrict__ old_s,  // [BATCH][HID]
                    const float* __restrict__ W_z,    // [MID][CONCAT]
                    const float* __restrict__ b_z,
                    const float* __restrict__ W_s,    // [HID][ZS]
                    const float* __restrict__ b_s,
                    const float* __restrict__ W_m,    // [HID][ZS]
                    const float* __restrict__ b_m,
                    float* __restrict__ out)
{
    const int bid = blockIdx.x;
    const int b   = bid & 63;      // batch
    const int w   = bid >> 6;      // quarter
    const int tid = threadIdx.x;
    const int h   = tid;           // phase-B / finish row (global h)

    __shared__ __align__(16) uint32_t zin[16 * 36]; // [x|m|1/s] fp16 pairs, chunked
    __shared__ __align__(16) uint32_t zvec[40];     // [x-slice(8) | z-quarter(32)]

    const int g = tid >> 4, c = tid & 15;           // phase A: row pair, K-chunk

    // ---- one-time: weights -> VGPRs (fp16 RTN) ----
    uint32_t wA0[34], wA1[34];
    {
        const float* p0 = W_z + (size_t)(QZ * w + 2 * g) * CONCAT + 68 * c;
        const float* p1 = p0 + CONCAT;
        #pragma unroll
        for (int i = 0; i < 34; ++i) {
            float2 a  = *reinterpret_cast<const float2*>(p0 + 2 * i);
            float2 bb = *reinterpret_cast<const float2*>(p1 + 2 * i);
            wA0[i] = packrtn(a.x, a.y);
            wA1[i] = packrtn(bb.x, bb.y);
        }
    }
    uint32_t wS[40], wM[40];
    {
        const float* ps = W_s + (size_t)h * ZS;
        const float* pm = W_m + (size_t)h * ZS;
        #pragma unroll
        for (int i = 0; i < 8; ++i) {   // x-col slice: cols 16w+2i
            float2 a  = *reinterpret_cast<const float2*>(ps + 16 * w + 2 * i);
            float2 bb = *reinterpret_cast<const float2*>(pm + 16 * w + 2 * i);
            wS[i] = packrtn(a.x, a.y);
            wM[i] = packrtn(bb.x, bb.y);
        }
        #pragma unroll
        for (int i = 0; i < 32; ++i) {  // z-col slice: cols 64+64w+2i
            float2 a  = *reinterpret_cast<const float2*>(ps + 64 + 64 * w + 2 * i);
            float2 bb = *reinterpret_cast<const float2*>(pm + 64 + 64 * w + 2 * i);
            wS[8 + i] = packrtn(a.x, a.y);
            wM[8 + i] = packrtn(bb.x, bb.y);
        }
    }
    const float bz0 = b_z[QZ * w + 2 * g], bz1 = b_z[QZ * w + 2 * g + 1];
    const float bsv = b_s[h], bmv = b_m[h];

    // ---- registers: full per-h state (redundant across the 4 WGs) ----
    float sreg = old_s[b * HID + h];
    float mreg = old_m[b * HID + h];

    // x prefetch: threads 0..31 hold float pair (2*tid, 2*tid+1)
    float2 xv = {0.f, 0.f};
    if (tid < 32) xv = *reinterpret_cast<const float2*>(x + (size_t)b * IN_ + 2 * tid);

    // ---- initial staging of zin(t=0) and zvec x-slice ----
    if (tid < 256) {
        float2 mv = *reinterpret_cast<const float2*>(old_m + b * HID + 2 * tid);
        zin[zidx(32 + tid)] = packrtn(mv.x, mv.y);
    } else {
        const int j = tid - 256;
        float2 sv = *reinterpret_cast<const float2*>(old_s + b * HID + 2 * j);
        zin[zidx(288 + j)] = packrtn(__builtin_amdgcn_rcpf(sv.x),
                                     __builtin_amdgcn_rcpf(sv.y));
    }
    if (tid < 32) zin[zidx(tid)] = packrtn(xv.x, xv.y);
    if (tid >= 8 * w && tid < 8 * w + 8) zvec[tid - 8 * w] = packrtn(xv.x, xv.y);
    __syncthreads();

    float* __restrict__ out_m = out;
    float* __restrict__ out_s = out + (size_t)SEQ * BATCH * HID;

    for (int t = 0; t < SEQ; ++t) {
        const int par = t & 1;
        const uint64_t want = (uint64_t)(t + 1);

        // ---- phase A: z_mid rows (64w+2g, +1), K split over 16 lanes ----
        {
            uint32_t zf[34];
            const uint32_t* zc = &zin[c * 36];
            #pragma unroll
            for (int i = 0; i < 8; ++i) {
                uint4 v = *reinterpret_cast<const uint4*>(zc + 4 * i);
                zf[4 * i] = v.x; zf[4 * i + 1] = v.y; zf[4 * i + 2] = v.z; zf[4 * i + 3] = v.w;
            }
            { uint2 v = *reinterpret_cast<const uint2*>(zc + 32); zf[32] = v.x; zf[33] = v.y; }
            float a0 = 0.f, a1 = 0.f;
            #pragma unroll
            for (int i = 0; i < 34; ++i) {
                a0 = fdot2u(wA0[i], zf[i], a0);
                a1 = fdot2u(wA1[i], zf[i], a1);
            }
            a0 = red16(a0);
            a1 = red16(a1);
            if (c == 0)
                zvec[8 + g] = packrtn(tanhf(a0 + bz0), tanhf(a1 + bz1));
        }
        __syncthreads();   // zvec z-quarter visible to phase B

        // ---- phase B: partial (s,m) for row h over this WG's 80-col slice ----
        float as = 0.f, am = 0.f;
        {
            uint32_t zg[40];
            #pragma unroll
            for (int i = 0; i < 10; ++i) {
                uint4 v = *reinterpret_cast<const uint4*>(&zvec[4 * i]);
                zg[4 * i] = v.x; zg[4 * i + 1] = v.y; zg[4 * i + 2] = v.z; zg[4 * i + 3] = v.w;
            }
            #pragma unroll
            for (int i = 0; i < 40; ++i) {
                as = fdot2u(wS[i], zg[i], as);
                am = fdot2u(wM[i], zg[i], am);
            }
        }
        // publish stamped word: {t+1, packed partials}
        {
            const uint64_t word = (want << 32) | (uint64_t)packrtn(as, am);
            __hip_atomic_store(&g_px[(((size_t)b * 2 + par) * NW + w) * HID + h],
                               word, __ATOMIC_RELAXED, __HIP_MEMORY_SCOPE_AGENT);
        }
        // Barrier: (a) all zvec reads of step t done -> staging may overwrite;
        // (b) all px stores issued (drained by barrier's vmcnt wait).
        __syncthreads();

        // x prefetch for t+1 issues here; overlaps with poll + finish
        if (tid < 32 && t + 1 < SEQ)
            xv = *reinterpret_cast<const float2*>(
                x + ((size_t)(t + 1) * BATCH + b) * IN_ + 2 * tid);

        // ---- poll 3 peers' stamped words for row h, accumulate ----
        #pragma unroll
        for (int p = 0; p < 3; ++p) {
            const int w2 = (w + 1 + p) & 3;
            const uint64_t* src = &g_px[(((size_t)b * 2 + par) * NW + w2) * HID + h];
            uint64_t pw;
            do {
                pw = __hip_atomic_load(src, __ATOMIC_RELAXED, __HIP_MEMORY_SCOPE_AGENT);
            } while ((pw >> 32) != want);
            h2t hv = __builtin_bit_cast(h2t, (uint32_t)pw);
            as += (float)hv.x;
            am += (float)hv.y;
        }

        // ---- finish: state update for row h (redundant in all 4 WGs) ----
        const float sig  = 1.f / (1.f + expf(-(as + bsv)));
        const float ns   = sreg + sig;
        const float gate = sreg / ns;              // stop-grad: old_s / new_s
        const float nm   = gate * mreg + (1.f - gate) * tanhf(am + bmv);
        const float inv  = __builtin_amdgcn_rcpf(ns);
        sreg = ns; mreg = nm;

        // owner WG writes output for its h-quarter
        if ((h >> 7) == w) {
            const size_t o = ((size_t)t * BATCH + b) * HID + h;
            out_m[o] = nm;
            out_s[o] = ns;
        }

        // ---- stage zin(t+1) + zvec x-slice in-register (DPP pair swap) ----
        const float nm_n  = dpp_get<0xB1>(nm);     // neighbor lane^1 value
        const float inv_n = dpp_get<0xB1>(inv);
        if ((tid & 1) == 0) {
            zin[zidx(32 + (tid >> 1))]  = packrtn(nm, nm_n);
            zin[zidx(288 + (tid >> 1))] = packrtn(inv, inv_n);
        }
        if (t + 1 < SEQ) {
            if (tid < 32) zin[zidx(tid)] = packrtn(xv.x, xv.y);
            if (tid >= 8 * w && tid < 8 * w + 8)
                zvec[tid - 8 * w] = packrtn(xv.x, xv.y);
        }
        __syncthreads();   // staging stable before next phase A
    }
}

extern "C" void kernel_launch(void* const* d_in, const int* in_sizes, int n_in,
                              void* d_out, int out_size, void* d_ws, size_t ws_size,
                              hipStream_t stream) {
    const float* x     = (const float*)d_in[0];
    const float* old_m = (const float*)d_in[1];
    const float* old_s = (const float*)d_in[2];
    const float* W_z   = (const float*)d_in[3];
    const float* b_z   = (const float*)d_in[4];
    const float* W_s   = (const float*)d_in[5];
    const float* b_s   = (const float*)d_in[6];
    const float* W_m   = (const float*)d_in[7];
    const float* b_m   = (const float*)d_in[8];

    metamu6_kernel<<<dim3(BATCH * NW), dim3(512), 0, stream>>>(
        x, old_m, old_s, W_z, b_z, W_s, b_s, W_m, b_m, (float*)d_out);
}